// Round 5
// baseline (520.498 us; speedup 1.0000x reference)
//
#include <hip/hip_runtime.h>
#include <math.h>

// Problem constants
#define NTOK 8192       // B*N tokens
#define DIM 768
#define SEQ 1024
#define NH 12
#define HD 64
#define HID 3072
#define S1V 320
#define S2V 384

typedef unsigned short bfu;   // bf16 storage
typedef __attribute__((ext_vector_type(8))) short short8;
typedef __attribute__((ext_vector_type(4))) float f32x4;

__device__ __forceinline__ bfu f2bf(float f){
  unsigned int u = __float_as_uint(f);
  u += 0x7FFFu + ((u >> 16) & 1u);      // RNE
  return (bfu)(u >> 16);
}
__device__ __forceinline__ f32x4 mfma16(short8 a, short8 b, f32x4 c){
  return __builtin_amdgcn_mfma_f32_16x16x32_bf16(a, b, c, 0, 0, 0);
}
__device__ __forceinline__ void gll16(const void* g, void* l){
  __builtin_amdgcn_global_load_lds(
      (const __attribute__((address_space(1))) unsigned int*)g,
      (__attribute__((address_space(3))) unsigned int*)l, 16, 0, 0);
}
// XOR-swizzle: fold 128B-granule index bits into the 16B-slot bits.
// Involution; preserves bits [3:0] so 16B loads stay contiguous.
__device__ __forceinline__ int swz(int a){ return a ^ (((a >> 7) & 7) << 4); }
__device__ __forceinline__ int swz2(int a){ return a ^ (((a >> 7) & 7) << 4); }

// ---------------- fp32 -> bf16 convert (weights) ----------------
__global__ __launch_bounds__(256) void cvt_kernel(const float4* __restrict__ src,
                                                  ushort4* __restrict__ dst, int n4){
  for (int i = blockIdx.x * 256 + threadIdx.x; i < n4; i += gridDim.x * 256){
    float4 f = src[i];
    ushort4 o;
    o.x = f2bf(f.x); o.y = f2bf(f.y); o.z = f2bf(f.z); o.w = f2bf(f.w);
    dst[i] = o;
  }
}

// ---------------- split LayerNorm: segments [0,320),[320,384),[384,768) ----------------
__global__ __launch_bounds__(256) void ln_split(
    const float* __restrict__ x,
    const float* __restrict__ ga, const float* __restrict__ ba,
    const float* __restrict__ gb, const float* __restrict__ bb2,
    const float* __restrict__ gc, const float* __restrict__ bc,
    bfu* __restrict__ out)
{
  const int row = blockIdx.x, t = threadIdx.x;
  const float* xr = x + (size_t)row * DIM;
  const float e0 = xr[t], e1 = xr[t + 256], e2 = xr[t + 512];
  float s0 = e0, q0 = e0 * e0, s1 = 0.f, q1 = 0.f, s2 = e2, q2 = e2 * e2;
  const int i1 = t + 256;
  if (i1 < S1V)      { s0 += e1; q0 += e1 * e1; }
  else if (i1 < S2V) { s1 += e1; q1 += e1 * e1; }
  else               { s2 += e1; q2 += e1 * e1; }
  float v[6] = {s0, q0, s1, q1, s2, q2};
  #pragma unroll
  for (int k = 0; k < 6; ++k)
    #pragma unroll
    for (int off = 32; off; off >>= 1)
      v[k] += __shfl_xor(v[k], off);
  __shared__ float red[6][4];
  const int lane = t & 63, wave = t >> 6;
  if (lane == 0){
    #pragma unroll
    for (int k = 0; k < 6; ++k) red[k][wave] = v[k];
  }
  __syncthreads();
  float tt[6];
  #pragma unroll
  for (int k = 0; k < 6; ++k) tt[k] = red[k][0] + red[k][1] + red[k][2] + red[k][3];
  const float m0 = tt[0] * (1.f/320.f);
  const float r0 = rsqrtf(tt[1] * (1.f/320.f) - m0*m0 + 1e-5f);
  const float m1 = tt[2] * (1.f/64.f);
  const float r1 = rsqrtf(tt[3] * (1.f/64.f) - m1*m1 + 1e-5f);
  const float m2 = tt[4] * (1.f/384.f);
  const float r2 = rsqrtf(tt[5] * (1.f/384.f) - m2*m2 + 1e-5f);
  bfu* orow = out + (size_t)row * DIM;
  orow[t] = f2bf((e0 - m0) * r0 * ga[t] + ba[t]);
  {
    float ov;
    if (i1 < S1V)      ov = (e1 - m0) * r0 * ga[i1] + ba[i1];
    else if (i1 < S2V) ov = (e1 - m1) * r1 * gb[i1 - S1V] + bb2[i1 - S1V];
    else               ov = (e1 - m2) * r2 * gc[i1 - S2V] + bc[i1 - S2V];
    orow[i1] = f2bf(ov);
  }
  const int i2 = t + 512;
  orow[i2] = f2bf((e2 - m2) * r2 * gc[i2 - S2V] + bc[i2 - S2V]);
}

// ---------------- gemm8p: 256x256 tile, BK=64, 8 waves, 8-phase counted-vmcnt schedule ----
// Per K-tile: 4 phases x {ds-reads, 1 half-tile stage, barrier, 16 MFMA, barrier}.
// Stage schedule (iter t): ph1/ph2 stage A-halves of tile t+1 -> other slot (free since
// iter t-1 end); ph3/ph4 stage B-halves of tile t+2 -> CURRENT slot (B fully consumed in
// ph1 of this iter). Boundary: vmcnt(4) (=2 half-tiles in flight) + one barrier; vmcnt(8)
// at t=0, vmcnt(0) at the last boundary. Loads never drain to 0 in steady state (T4).
template<int BIAS, int GELU_, int RESID, int OUTF32, int QSC>
__global__ __launch_bounds__(512, 2) void gemm8p(
    const bfu* __restrict__ A, const bfu* __restrict__ Bw,
    int N, int K, int ntn,
    const float* __restrict__ bias, const float* __restrict__ resid,
    float* __restrict__ outf, bfu* __restrict__ outb)
{
  __shared__ __align__(16) char lds[2][2][32768];   // [slot][A=0/B=1][256 rows x 128B]
  const int tid = threadIdx.x;
  const int lane = tid & 63;
  const int wave = tid >> 6;
  const int wm = wave >> 2, wn = wave & 3;
  const int r = lane & 15, g = lane >> 4;
  const int sx = (r & 7) << 4;                      // swizzle XOR for fragment reads

  // T1 XCD-aware grid swizzle (all grids % 8 == 0)
  const int nwg = gridDim.x, cpx = nwg >> 3;
  const int sb = (blockIdx.x & 7) * cpx + (blockIdx.x >> 3);
  const int tm = sb / ntn, tn = sb % ntn;

  const size_t ld2 = (size_t)K * 2;                  // row stride in bytes

  f32x4 acc[8][4];
  #pragma unroll
  for (int i = 0; i < 8; ++i)
    #pragma unroll
    for (int j = 0; j < 4; ++j) acc[i][j] = (f32x4){0.f, 0.f, 0.f, 0.f};

  // staging geometry: 512 thr x 16B x 2 issues cover one 16KB half-tile (128 rows x 128B)
  const int Ls = swz2(tid * 16);                     // logical offset for phys tid*16
  const int r0 = Ls >> 7;                            // 0..63 row within an 8KB chunk
  const int c0 = Ls & 127;                           // 16B-aligned byte col
  const char* Abase = (const char*)A + (size_t)tm * 256 * ld2 + c0;
  const char* Bbase = (const char*)Bw + (size_t)tn * 256 * ld2 + c0;
  const int tid16 = tid * 16;
  const int nt = K >> 6;

  // stage half h (0/1) of matrix mx (0=A,1=B) of K-tile t into slot slt
  #define SHALF(mx, slt, h, t) do { \
    const char* gb = ((mx) ? Bbase : Abase) + (size_t)(t) * 128; \
    _Pragma("unroll") \
    for (int j = 0; j < 2; ++j) \
      gll16(gb + (size_t)(((h) * 2 + j) * 64 + r0) * ld2, \
            &lds[slt][mx][((h) * 2 + j) * 8192 + tid16]); \
  } while (0)

  #define LDA(lA, p) do { \
    _Pragma("unroll") \
    for (int mm = 0; mm < 2; ++mm) \
      _Pragma("unroll") \
      for (int h2 = 0; h2 < 2; ++h2) \
        afr[mm][h2] = *(const short8*)((lA) + ((((wm * 128 + ((p) * 2 + mm) * 16 + r) * 128) + h2 * 64 + g * 16) ^ sx)); \
  } while (0)

  #define MM(p) do { \
    __builtin_amdgcn_s_setprio(1); \
    _Pragma("unroll") \
    for (int mm = 0; mm < 2; ++mm) \
      _Pragma("unroll") \
      for (int n = 0; n < 4; ++n){ \
        acc[(p) * 2 + mm][n] = mfma16(afr[mm][0], bfr[n][0], acc[(p) * 2 + mm][n]); \
        acc[(p) * 2 + mm][n] = mfma16(afr[mm][1], bfr[n][1], acc[(p) * 2 + mm][n]); \
      } \
    __builtin_amdgcn_s_setprio(0); \
  } while (0)

  // prologue: fully stage tiles 0 (slot0) and 1 (slot1) — 16 gll
  SHALF(0, 0, 0, 0); SHALF(0, 0, 1, 0); SHALF(1, 0, 0, 0); SHALF(1, 0, 1, 0);
  SHALF(0, 1, 0, 1); SHALF(0, 1, 1, 1); SHALF(1, 1, 0, 1); SHALF(1, 1, 1, 1);

  for (int t = 0; t < nt; ++t){
    const int s = t & 1;
    // iteration boundary: counted vmcnt, then single barrier
    if (t == 0)            asm volatile("s_waitcnt vmcnt(8)" ::: "memory");
    else if (t + 1 < nt)   asm volatile("s_waitcnt vmcnt(4)" ::: "memory");
    else                   asm volatile("s_waitcnt vmcnt(0)" ::: "memory");
    __builtin_amdgcn_sched_barrier(0);
    __builtin_amdgcn_s_barrier();

    const char* lA = lds[s][0];
    const char* lB = lds[s][1];
    short8 bfr[4][2];
    short8 afr[2][2];

    // ---- phase 1: all B-frags + A-pair0; stage A-half0(t+1) -> slot s^1
    #pragma unroll
    for (int n = 0; n < 4; ++n)
      #pragma unroll
      for (int h2 = 0; h2 < 2; ++h2)
        bfr[n][h2] = *(const short8*)(lB + ((((wn * 64 + n * 16 + r) * 128) + h2 * 64 + g * 16) ^ sx));
    LDA(lA, 0);
    if (t >= 1 && t + 1 < nt) SHALF(0, s ^ 1, 0, t + 1);
    __builtin_amdgcn_s_barrier();
    MM(0);
    __builtin_amdgcn_s_barrier();
    // ---- phase 2: A-pair1; stage A-half1(t+1) -> slot s^1
    LDA(lA, 1);
    if (t >= 1 && t + 1 < nt) SHALF(0, s ^ 1, 1, t + 1);
    __builtin_amdgcn_s_barrier();
    MM(1);
    __builtin_amdgcn_s_barrier();
    // ---- phase 3: A-pair2; stage B-half0(t+2) -> slot s (B consumed in ph1)
    LDA(lA, 2);
    if (t + 2 < nt) SHALF(1, s, 0, t + 2);
    __builtin_amdgcn_s_barrier();
    MM(2);
    __builtin_amdgcn_s_barrier();
    // ---- phase 4: A-pair3; stage B-half1(t+2) -> slot s; end barrier = next boundary
    LDA(lA, 3);
    if (t + 2 < nt) SHALF(1, s, 1, t + 2);
    __builtin_amdgcn_s_barrier();
    MM(3);
    // (no trailing barrier: the next iteration's boundary barrier covers it)
  }
  #undef SHALF
  #undef LDA
  #undef MM

  // epilogue: C/D frag layout col=lane&15(r), row=(lane>>4)*4+q (g,q)
  const int row0 = tm * 256 + wm * 128;
  const int col0 = tn * 256 + wn * 64;
  #pragma unroll
  for (int n = 0; n < 4; ++n){
    const int colb = col0 + n * 16 + r;
    const float bi = BIAS ? bias[colb] : 0.f;
    #pragma unroll
    for (int m = 0; m < 8; ++m){
      #pragma unroll
      for (int q = 0; q < 4; ++q){
        const int rowg = row0 + m * 16 + g * 4 + q;
        float v = acc[m][n][q] + bi;
        if (GELU_) v = 0.5f * v * (1.f + erff(v * 0.70710678118654752440f));
        if (QSC && colb < 768) v *= 0.125f;           // fold attention scale into Q
        const size_t idx = (size_t)rowg * N + colb;
        float vv = v;
        if (RESID) vv += resid[idx];
        if (OUTF32) outf[idx] = vv;
        else        outb[idx] = f2bf(vv);
      }
    }
  }
}

// ---------------- V transpose: qkv[:,1536+h*64+d] -> vt[bh][d][k] ----------------
__global__ __launch_bounds__(256) void vtrans(const bfu* __restrict__ qkv, bfu* __restrict__ vt){
  __shared__ bfu tile[64][66];
  const int bh = blockIdx.x, kt = blockIdx.y;
  const int b = bh / NH, h = bh - b * NH;
  const int tid = threadIdx.x;
  const int tr = tid >> 5;
  const int tc = (tid & 31) * 2;
  #pragma unroll
  for (int pass = 0; pass < 8; ++pass){
    const int k = pass * 8 + tr;
    const bfu* src = qkv + (size_t)(b * SEQ + kt * 64 + k) * 2304 + 1536 + h * 64 + tc;
    tile[k][tc] = src[0]; tile[k][tc + 1] = src[1];
  }
  __syncthreads();
  #pragma unroll
  for (int pass = 0; pass < 8; ++pass){
    const int d = pass * 8 + tr;
    bfu* dst = vt + ((size_t)bh * 64 + d) * SEQ + kt * 64 + tc;
    dst[0] = tile[tc][d]; dst[1] = tile[tc + 1][d];
  }
}

// ---------------- flash attention v2: 8 waves/block, LDS-staged K/V, double-buffered ----------
__global__ __launch_bounds__(512) void attn2(
    const bfu* __restrict__ qkv, const bfu* __restrict__ vt, bfu* __restrict__ y)
{
  __shared__ __align__(16) char kbuf[2][8192];
  __shared__ __align__(16) char vbuf[2][8192];
  __shared__ __align__(16) char plds_all[8][2048];
  const int tid = threadIdx.x, lane = tid & 63, wave = tid >> 6;
  char* plds = plds_all[wave];
  const int blk = blockIdx.x;                 // 768 blocks
  const int bh = blk >> 3, q128 = blk & 7;
  const int b = bh / NH, h = bh - b * NH;
  const int r = lane & 15, g = lane >> 4;

  const bfu* qbase = qkv + (size_t)(b * SEQ + q128 * 128 + wave * 16 + r) * 2304 + h * 64;
  const short8 qf0 = *(const short8*)(qbase + g * 8);
  const short8 qf1 = *(const short8*)(qbase + 32 + g * 8);

  const int P = tid * 16;
  const int Ls = swz(P);
  const int srow = Ls >> 7, scol = Ls & 127;
  const char* kg = (const char*)(qkv + (size_t)(b * SEQ) * 2304 + 768 + h * 64)
                   + (size_t)srow * 4608 + scol;
  const char* vg = (const char*)(vt + (size_t)bh * 64 * SEQ)
                   + (size_t)srow * 2048 + scol;

  int off[4][2];
  #pragma unroll
  for (int f = 0; f < 4; ++f){
    off[f][0] = swz((f * 16 + r) * 128 + g * 16);
    off[f][1] = swz((f * 16 + r) * 128 + 64 + g * 16);
  }

  float m_[4], l_[4];
  f32x4 yacc[4];
  #pragma unroll
  for (int i = 0; i < 4; ++i){ m_[i] = -1e30f; l_[i] = 0.f; yacc[i] = (f32x4){0.f,0.f,0.f,0.f}; }

  gll16(kg, &kbuf[0][P]);
  gll16(vg, &vbuf[0][P]);
  __syncthreads();

  for (int kt = 0; kt < 16; ++kt){
    const int cur = kt & 1;
    if (kt + 1 < 16){
      gll16(kg + (size_t)(kt + 1) * 294912, &kbuf[cur ^ 1][P]);   // 64 rows * 4608B
      gll16(vg + (kt + 1) * 128, &vbuf[cur ^ 1][P]);
    }
    const char* lK = kbuf[cur];
    const char* lV = vbuf[cur];

    f32x4 s[4];
    #pragma unroll
    for (int c = 0; c < 4; ++c){
      const short8 kf0 = *(const short8*)(lK + off[c][0]);
      const short8 kf1 = *(const short8*)(lK + off[c][1]);
      s[c] = (f32x4){0.f, 0.f, 0.f, 0.f};
      s[c] = mfma16(qf0, kf0, s[c]);
      s[c] = mfma16(qf1, kf1, s[c]);
    }
    float pm[4];
    #pragma unroll
    for (int q = 0; q < 4; ++q)
      pm[q] = fmaxf(fmaxf(s[0][q], s[1][q]), fmaxf(s[2][q], s[3][q]));
    #pragma unroll
    for (int q = 0; q < 4; ++q)
      #pragma unroll
      for (int o = 1; o < 16; o <<= 1)
        pm[q] = fmaxf(pm[q], __shfl_xor(pm[q], o));
    float rs[4];
    #pragma unroll
    for (int q = 0; q < 4; ++q){
      const float mn = fmaxf(m_[q], pm[q]);
      const float al = __expf(m_[q] - mn);
      m_[q] = mn;
      l_[q] *= al;
      #pragma unroll
      for (int f = 0; f < 4; ++f) yacc[f][q] *= al;
      float acc = 0.f;
      #pragma unroll
      for (int c = 0; c < 4; ++c){
        const float p = __expf(s[c][q] - mn);
        s[c][q] = p;
        acc += p;
      }
      rs[q] = acc;
    }
    #pragma unroll
    for (int q = 0; q < 4; ++q){
      #pragma unroll
      for (int o = 1; o < 16; o <<= 1)
        rs[q] += __shfl_xor(rs[q], o);
      l_[q] += rs[q];
    }
    #pragma unroll
    for (int c = 0; c < 4; ++c)
      #pragma unroll
      for (int q = 0; q < 4; ++q){
        const int a = swz((g * 4 + q) * 128 + (c * 16 + r) * 2);
        *(bfu*)&plds[a] = f2bf(s[c][q]);
      }
    short8 pa[2];
    #pragma unroll
    for (int ks = 0; ks < 2; ++ks)
      pa[ks] = *(const short8*)&plds[swz(r * 128 + ks * 64 + g * 16)];
    #pragma unroll
    for (int f = 0; f < 4; ++f){
      const short8 vf0 = *(const short8*)(lV + off[f][0]);
      const short8 vf1 = *(const short8*)(lV + off[f][1]);
      yacc[f] = mfma16(pa[0], vf0, yacc[f]);
      yacc[f] = mfma16(pa[1], vf1, yacc[f]);
    }
    __syncthreads();
  }

  bfu* yb = y + (size_t)(b * SEQ + q128 * 128 + wave * 16) * DIM + h * 64;
  #pragma unroll
  for (int f = 0; f < 4; ++f)
    #pragma unroll
    for (int q = 0; q < 4; ++q)
      yb[(size_t)(g * 4 + q) * DIM + f * 16 + r] = f2bf(yacc[f][q] / l_[q]);
}

// ---------------- launch ----------------
extern "C" void kernel_launch(void* const* d_in, const int* in_sizes, int n_in,
                              void* d_out, int out_size, void* d_ws, size_t ws_size,
                              hipStream_t stream) {
  const float* x      = (const float*)d_in[0];
  const float* ln1ag  = (const float*)d_in[1];
  const float* ln1ab  = (const float*)d_in[2];
  const float* ln1bg  = (const float*)d_in[3];
  const float* ln1bb  = (const float*)d_in[4];
  const float* ln1cg  = (const float*)d_in[5];
  const float* ln1cb  = (const float*)d_in[6];
  const float* ln2ag  = (const float*)d_in[7];
  const float* ln2ab  = (const float*)d_in[8];
  const float* ln2bg  = (const float*)d_in[9];
  const float* ln2bb  = (const float*)d_in[10];
  const float* ln2cg  = (const float*)d_in[11];
  const float* ln2cb  = (const float*)d_in[12];
  const float* qkv_w  = (const float*)d_in[13];
  const float* proj_w = (const float*)d_in[14];
  const float* proj_b = (const float*)d_in[15];
  const float* fc1_w  = (const float*)d_in[16];
  const float* fc1_b  = (const float*)d_in[17];
  const float* fc2_w  = (const float*)d_in[18];
  const float* fc2_b  = (const float*)d_in[19];
  float* outp = (float*)d_out;

  char* ws = (char*)d_ws;
  bfu* wqkv   = (bfu*)(ws + 0);            // 2304*768*2  = 3,538,944
  bfu* wproj  = (bfu*)(ws + 3538944);      //  768*768*2  = 1,179,648
  bfu* wfc1   = (bfu*)(ws + 4718592);      // 3072*768*2  = 4,718,592
  bfu* wfc2   = (bfu*)(ws + 9437184);      //  768*3072*2 = 4,718,592
  bfu* lnbuf  = (bfu*)(ws + 14155776);     // 8192*768*2  = 12,582,912
  bfu* ybuf   = (bfu*)(ws + 26738688);     // 8192*768*2  = 12,582,912
  bfu* qkvbuf = (bfu*)(ws + 39321600);     // 8192*2304*2 = 37,748,736
  bfu* vtbuf  = (bfu*)(ws + 77070336);     // 96*64*1024*2= 12,582,912  (end ~89.7MB)
  bfu* hbuf   = qkvbuf;                    // reuse qkv+vt region: 8192*3072*2 = 50,331,648

  // weights -> bf16
  cvt_kernel<<<512, 256, 0, stream>>>((const float4*)qkv_w,  (ushort4*)wqkv, 2304*768/4);
  cvt_kernel<<<256, 256, 0, stream>>>((const float4*)proj_w, (ushort4*)wproj, 768*768/4);
  cvt_kernel<<<512, 256, 0, stream>>>((const float4*)fc1_w,  (ushort4*)wfc1, 3072*768/4);
  cvt_kernel<<<512, 256, 0, stream>>>((const float4*)fc2_w,  (ushort4*)wfc2, 768*3072/4);

  // LN1
  ln_split<<<NTOK, 256, 0, stream>>>(x, ln1ag, ln1ab, ln1bg, ln1bb, ln1cg, ln1cb, lnbuf);
  // QKV (Q scaled by 0.125 in epilogue): 32x9 = 288 blocks
  gemm8p<0,0,0,0,1><<<288, 512, 0, stream>>>(lnbuf, wqkv, 2304, 768, 9,
                                             nullptr, nullptr, nullptr, qkvbuf);
  // V transpose for PV B-operand
  vtrans<<<dim3(96,16), 256, 0, stream>>>(qkvbuf, vtbuf);
  // attention (staged K/V, double-buffered)
  attn2<<<768, 512, 0, stream>>>(qkvbuf, vtbuf, ybuf);
  // proj + bias + residual(x) -> d_out (fp32): 32x3 = 96 blocks
  gemm8p<1,0,1,1,0><<<96, 512, 0, stream>>>(ybuf, wproj, 768, 768, 3,
                                            proj_b, x, outp, nullptr);
  // LN2
  ln_split<<<NTOK, 256, 0, stream>>>(outp, ln2ag, ln2ab, ln2bg, ln2bb, ln2cg, ln2cb, lnbuf);
  // FC1 + bias + GELU -> h (bf16): 32x12 = 384 blocks
  gemm8p<1,1,0,0,0><<<384, 512, 0, stream>>>(lnbuf, wfc1, 3072, 768, 12,
                                             fc1_b, nullptr, nullptr, hbuf);
  // FC2 + bias + residual(d_out) -> d_out (fp32, in-place): K=3072, 32x3 = 96 blocks
  gemm8p<1,0,1,1,0><<<96, 512, 0, stream>>>(hbuf, wfc2, 768, 3072, 3,
                                            fc2_b, outp, outp, nullptr);
}

// Round 6
// 456.965 us; speedup vs baseline: 1.1390x; 1.1390x over previous
//
#include <hip/hip_runtime.h>
#include <math.h>

// Problem constants
#define NTOK 8192       // B*N tokens
#define DIM 768
#define SEQ 1024
#define NH 12
#define HD 64
#define HID 3072
#define S1V 320
#define S2V 384

typedef unsigned short bfu;   // bf16 storage
typedef __attribute__((ext_vector_type(8))) short short8;
typedef __attribute__((ext_vector_type(4))) float f32x4;

__device__ __forceinline__ bfu f2bf(float f){
  unsigned int u = __float_as_uint(f);
  u += 0x7FFFu + ((u >> 16) & 1u);      // RNE
  return (bfu)(u >> 16);
}
__device__ __forceinline__ f32x4 mfma16(short8 a, short8 b, f32x4 c){
  return __builtin_amdgcn_mfma_f32_16x16x32_bf16(a, b, c, 0, 0, 0);
}
__device__ __forceinline__ void gll16(const void* g, void* l){
  __builtin_amdgcn_global_load_lds(
      (const __attribute__((address_space(1))) unsigned int*)g,
      (__attribute__((address_space(3))) unsigned int*)l, 16, 0, 0);
}
// XOR-swizzle: fold bits[9:7] into the 16B-slot bits[6:4]. Involution;
// preserves bits [3:0] so 16B loads stay contiguous.
__device__ __forceinline__ int swz(int a){ return a ^ (((a >> 7) & 7) << 4); }

// ---------------- fp32 -> bf16 convert (all four weights, one launch) ----------------
__global__ __launch_bounds__(256) void cvt_all(
    const float4* __restrict__ s0, ushort4* __restrict__ d0,   // qkv_w  442368 f4
    const float4* __restrict__ s1, ushort4* __restrict__ d1,   // proj_w 147456
    const float4* __restrict__ s2, ushort4* __restrict__ d2,   // fc1_w  589824
    const float4* __restrict__ s3, ushort4* __restrict__ d3)   // fc2_w  589824
{
  const int total = 1769472;
  for (int i = blockIdx.x * 256 + threadIdx.x; i < total; i += gridDim.x * 256){
    const float4* s; ushort4* d; int j = i;
    if (j < 442368)       { s = s0; d = d0; }
    else if (j < 589824)  { s = s1; d = d1; j -= 442368; }
    else if (j < 1179648) { s = s2; d = d2; j -= 589824; }
    else                  { s = s3; d = d3; j -= 1179648; }
    float4 f = s[j];
    ushort4 o;
    o.x = f2bf(f.x); o.y = f2bf(f.y); o.z = f2bf(f.z); o.w = f2bf(f.w);
    d[j] = o;
  }
}

// ---------------- split LayerNorm: segments [0,320),[320,384),[384,768) ----------------
__global__ __launch_bounds__(256) void ln_split(
    const float* __restrict__ x,
    const float* __restrict__ ga, const float* __restrict__ ba,
    const float* __restrict__ gb, const float* __restrict__ bb2,
    const float* __restrict__ gc, const float* __restrict__ bc,
    bfu* __restrict__ out)
{
  const int row = blockIdx.x, t = threadIdx.x;
  const float* xr = x + (size_t)row * DIM;
  const float e0 = xr[t], e1 = xr[t + 256], e2 = xr[t + 512];
  float s0 = e0, q0 = e0 * e0, s1 = 0.f, q1 = 0.f, s2 = e2, q2 = e2 * e2;
  const int i1 = t + 256;
  if (i1 < S1V)      { s0 += e1; q0 += e1 * e1; }
  else if (i1 < S2V) { s1 += e1; q1 += e1 * e1; }
  else               { s2 += e1; q2 += e1 * e1; }
  float v[6] = {s0, q0, s1, q1, s2, q2};
  #pragma unroll
  for (int k = 0; k < 6; ++k)
    #pragma unroll
    for (int off = 32; off; off >>= 1)
      v[k] += __shfl_xor(v[k], off);
  __shared__ float red[6][4];
  const int lane = t & 63, wave = t >> 6;
  if (lane == 0){
    #pragma unroll
    for (int k = 0; k < 6; ++k) red[k][wave] = v[k];
  }
  __syncthreads();
  float tt[6];
  #pragma unroll
  for (int k = 0; k < 6; ++k) tt[k] = red[k][0] + red[k][1] + red[k][2] + red[k][3];
  const float m0 = tt[0] * (1.f/320.f);
  const float r0 = rsqrtf(tt[1] * (1.f/320.f) - m0*m0 + 1e-5f);
  const float m1 = tt[2] * (1.f/64.f);
  const float r1 = rsqrtf(tt[3] * (1.f/64.f) - m1*m1 + 1e-5f);
  const float m2 = tt[4] * (1.f/384.f);
  const float r2 = rsqrtf(tt[5] * (1.f/384.f) - m2*m2 + 1e-5f);
  bfu* orow = out + (size_t)row * DIM;
  orow[t] = f2bf((e0 - m0) * r0 * ga[t] + ba[t]);
  {
    float ov;
    if (i1 < S1V)      ov = (e1 - m0) * r0 * ga[i1] + ba[i1];
    else if (i1 < S2V) ov = (e1 - m1) * r1 * gb[i1 - S1V] + bb2[i1 - S1V];
    else               ov = (e1 - m2) * r2 * gc[i1 - S2V] + bc[i1 - S2V];
    orow[i1] = f2bf(ov);
  }
  const int i2 = t + 512;
  orow[i2] = f2bf((e2 - m2) * r2 * gc[i2 - S2V] + bc[i2 - S2V]);
}

// ---------------- GEMM core: C[M,N] = A[M,K] * W[N,K]^T, BK=32, 4 waves (2x2) -----------
// Block tile BM x BN = (FM*32) x (FN*32). 2-phase double-buffer with global_load_lds
// (XOR-swizzled source, rule #21), one __syncthreads per K-step (proven round-2 core).
// 24-32KB LDS -> 4-5 blocks/CU co-residency is the latency-hiding mechanism.
template<int FM, int FN, int BIAS, int GELU_, int RESID, int OUTF32, int QSC>
__device__ __forceinline__ void gemm_core(
    const bfu* __restrict__ A, const bfu* __restrict__ Bw,
    int N, int K, int ntn,
    const float* __restrict__ bias, const float* __restrict__ resid,
    float* __restrict__ outf, bfu* __restrict__ outb)
{
  constexpr int BM = FM * 32, BN = FN * 32;
  constexpr int ABYTES = BM * 64, BBYTES = BN * 64;   // one K-tile (BK=32) per matrix
  constexpr int AISS = ABYTES / 4096, BISS = BBYTES / 4096;
  __shared__ __align__(16) char lA_[2][ABYTES];
  __shared__ __align__(16) char lB_[2][BBYTES];
  const int tid = threadIdx.x;
  const int lane = tid & 63;
  const int wave = tid >> 6;
  const int wm = wave >> 1, wn = wave & 1;
  const int r = lane & 15, g = lane >> 4;

  // T1 XCD-aware grid swizzle (all grids % 8 == 0)
  const int nwg = gridDim.x, cpx = nwg >> 3;
  const int sb = (blockIdx.x & 7) * cpx + (blockIdx.x >> 3);
  const int tm = sb / ntn, tn = sb % ntn;
  const size_t ld2 = (size_t)K * 2;

  f32x4 acc[FM][FN];
  #pragma unroll
  for (int i = 0; i < FM; ++i)
    #pragma unroll
    for (int j = 0; j < FN; ++j) acc[i][j] = (f32x4){0.f, 0.f, 0.f, 0.f};

  // staging geometry: phys P covered linearly; logical L = swz(P) -> (row, byte-col)
  int PofA[AISS], rowA[AISS], colA[AISS];
  #pragma unroll
  for (int is = 0; is < AISS; ++is){
    const int P = is * 4096 + tid * 16, L = swz(P);
    PofA[is] = P; rowA[is] = L >> 6; colA[is] = L & 63;
  }
  int PofB[BISS], rowB[BISS], colB[BISS];
  #pragma unroll
  for (int is = 0; is < BISS; ++is){
    const int P = is * 4096 + tid * 16, L = swz(P);
    PofB[is] = P; rowB[is] = L >> 6; colB[is] = L & 63;
  }
  const char* Abase = (const char*)A + (size_t)tm * BM * ld2;
  const char* Bbase = (const char*)Bw + (size_t)tn * BN * ld2;

  // fragment read offsets (loop-invariant, swizzled)
  int offA[FM], offB[FN];
  #pragma unroll
  for (int f = 0; f < FM; ++f) offA[f] = swz((wm * FM * 16 + f * 16 + r) * 64 + g * 16);
  #pragma unroll
  for (int f = 0; f < FN; ++f) offB[f] = swz((wn * FN * 16 + f * 16 + r) * 64 + g * 16);

  const int nk = K >> 5;
  #pragma unroll
  for (int is = 0; is < AISS; ++is)
    gll16(Abase + (size_t)rowA[is] * ld2 + colA[is], &lA_[0][PofA[is]]);
  #pragma unroll
  for (int is = 0; is < BISS; ++is)
    gll16(Bbase + (size_t)rowB[is] * ld2 + colB[is], &lB_[0][PofB[is]]);
  __syncthreads();

  for (int t = 0; t < nk; ++t){
    const int cur = t & 1;
    if (t + 1 < nk){
      const int kb = (t + 1) * 64;              // byte offset of next K-tile
      #pragma unroll
      for (int is = 0; is < AISS; ++is)
        gll16(Abase + (size_t)rowA[is] * ld2 + kb + colA[is], &lA_[cur ^ 1][PofA[is]]);
      #pragma unroll
      for (int is = 0; is < BISS; ++is)
        gll16(Bbase + (size_t)rowB[is] * ld2 + kb + colB[is], &lB_[cur ^ 1][PofB[is]]);
    }
    const char* lA = lA_[cur];
    const char* lB = lB_[cur];
    short8 af[FM], bf[FN];
    #pragma unroll
    for (int f = 0; f < FM; ++f) af[f] = *(const short8*)(lA + offA[f]);
    #pragma unroll
    for (int f = 0; f < FN; ++f) bf[f] = *(const short8*)(lB + offB[f]);
    #pragma unroll
    for (int i = 0; i < FM; ++i)
      #pragma unroll
      for (int j = 0; j < FN; ++j)
        acc[i][j] = mfma16(af[i], bf[j], acc[i][j]);
    __syncthreads();
  }

  // epilogue: C/D layout col=lane&15, row=(lane>>4)*4+reg
  const int row0 = tm * BM + wm * FM * 16;
  const int col0 = tn * BN + wn * FN * 16;
  #pragma unroll
  for (int j = 0; j < FN; ++j){
    const int colb = col0 + j * 16 + r;
    const float bi = BIAS ? bias[colb] : 0.f;
    #pragma unroll
    for (int i = 0; i < FM; ++i){
      #pragma unroll
      for (int q = 0; q < 4; ++q){
        const int rowg = row0 + i * 16 + g * 4 + q;
        float v = acc[i][j][q] + bi;
        if (GELU_) v = 0.5f * v * (1.f + erff(v * 0.70710678118654752440f));
        if (QSC && colb < 768) v *= 0.125f;   // fold attention scale into Q
        const size_t idx = (size_t)rowg * N + colb;
        if (RESID) v += resid[idx];
        if (OUTF32) outf[idx] = v;
        else        outb[idx] = f2bf(v);
      }
    }
  }
}

// Named wrappers -> distinct Kernel_Name rows in rocprof (per-GEMM diagnosis)
__global__ __launch_bounds__(256) void gemm_qkv(const bfu* A, const bfu* Bw, bfu* out){
  gemm_core<4,4,0,0,0,0,1>(A, Bw, 2304, 768, 18, nullptr, nullptr, nullptr, out);
}
__global__ __launch_bounds__(256) void gemm_proj(const bfu* A, const bfu* Bw,
                                                 const float* bias, const float* resid, float* out){
  gemm_core<2,4,1,0,1,1,0>(A, Bw, 768, 768, 6, bias, resid, out, nullptr);
}
__global__ __launch_bounds__(256) void gemm_fc1(const bfu* A, const bfu* Bw,
                                                const float* bias, bfu* out){
  gemm_core<4,4,1,1,0,0,0>(A, Bw, 3072, 768, 24, bias, nullptr, nullptr, out);
}
__global__ __launch_bounds__(256) void gemm_fc2(const bfu* A, const bfu* Bw,
                                                const float* bias, float* out){
  gemm_core<2,4,1,0,1,1,0>(A, Bw, 768, 3072, 6, bias, out, out, nullptr);
}

// ---------------- V transpose: qkv[:,1536+h*64+d] -> vt[bh][d][k] ----------------
__global__ __launch_bounds__(256) void vtrans(const bfu* __restrict__ qkv, bfu* __restrict__ vt){
  __shared__ bfu tile[64][66];
  const int bh = blockIdx.x, kt = blockIdx.y;
  const int b = bh / NH, h = bh - b * NH;
  const int tid = threadIdx.x;
  const int tr = tid >> 5;
  const int tc = (tid & 31) * 2;
  #pragma unroll
  for (int pass = 0; pass < 8; ++pass){
    const int k = pass * 8 + tr;
    const bfu* src = qkv + (size_t)(b * SEQ + kt * 64 + k) * 2304 + 1536 + h * 64 + tc;
    tile[k][tc] = src[0]; tile[k][tc + 1] = src[1];
  }
  __syncthreads();
  #pragma unroll
  for (int pass = 0; pass < 8; ++pass){
    const int d = pass * 8 + tr;
    bfu* dst = vt + ((size_t)bh * 64 + d) * SEQ + kt * 64 + tc;
    dst[0] = tile[tc][d]; dst[1] = tile[tc + 1][d];
  }
}

// ---------------- flash attention v2: 8 waves/block, LDS-staged K/V, double-buffered ----------
__global__ __launch_bounds__(512) void attn2(
    const bfu* __restrict__ qkv, const bfu* __restrict__ vt, bfu* __restrict__ y)
{
  __shared__ __align__(16) char kbuf[2][8192];
  __shared__ __align__(16) char vbuf[2][8192];
  __shared__ __align__(16) char plds_all[8][2048];
  const int tid = threadIdx.x, lane = tid & 63, wave = tid >> 6;
  char* plds = plds_all[wave];
  const int blk = blockIdx.x;                 // 768 blocks
  const int bh = blk >> 3, q128 = blk & 7;
  const int b = bh / NH, h = bh - b * NH;
  const int r = lane & 15, g = lane >> 4;

  const bfu* qbase = qkv + (size_t)(b * SEQ + q128 * 128 + wave * 16 + r) * 2304 + h * 64;
  const short8 qf0 = *(const short8*)(qbase + g * 8);
  const short8 qf1 = *(const short8*)(qbase + 32 + g * 8);

  const int P = tid * 16;
  const int Ls = swz(P);
  const int srow = Ls >> 7, scol = Ls & 127;
  const char* kg = (const char*)(qkv + (size_t)(b * SEQ) * 2304 + 768 + h * 64)
                   + (size_t)srow * 4608 + scol;
  const char* vg = (const char*)(vt + (size_t)bh * 64 * SEQ)
                   + (size_t)srow * 2048 + scol;

  int off[4][2];
  #pragma unroll
  for (int f = 0; f < 4; ++f){
    off[f][0] = swz((f * 16 + r) * 128 + g * 16);
    off[f][1] = swz((f * 16 + r) * 128 + 64 + g * 16);
  }

  float m_[4], l_[4];
  f32x4 yacc[4];
  #pragma unroll
  for (int i = 0; i < 4; ++i){ m_[i] = -1e30f; l_[i] = 0.f; yacc[i] = (f32x4){0.f,0.f,0.f,0.f}; }

  gll16(kg, &kbuf[0][P]);
  gll16(vg, &vbuf[0][P]);
  __syncthreads();

  for (int kt = 0; kt < 16; ++kt){
    const int cur = kt & 1;
    if (kt + 1 < 16){
      gll16(kg + (size_t)(kt + 1) * 294912, &kbuf[cur ^ 1][P]);   // 64 rows * 4608B
      gll16(vg + (kt + 1) * 128, &vbuf[cur ^ 1][P]);
    }
    const char* lK = kbuf[cur];
    const char* lV = vbuf[cur];

    f32x4 s[4];
    #pragma unroll
    for (int c = 0; c < 4; ++c){
      const short8 kf0 = *(const short8*)(lK + off[c][0]);
      const short8 kf1 = *(const short8*)(lK + off[c][1]);
      s[c] = (f32x4){0.f, 0.f, 0.f, 0.f};
      s[c] = mfma16(qf0, kf0, s[c]);
      s[c] = mfma16(qf1, kf1, s[c]);
    }
    float pm[4];
    #pragma unroll
    for (int q = 0; q < 4; ++q)
      pm[q] = fmaxf(fmaxf(s[0][q], s[1][q]), fmaxf(s[2][q], s[3][q]));
    #pragma unroll
    for (int q = 0; q < 4; ++q)
      #pragma unroll
      for (int o = 1; o < 16; o <<= 1)
        pm[q] = fmaxf(pm[q], __shfl_xor(pm[q], o));
    float rs[4];
    #pragma unroll
    for (int q = 0; q < 4; ++q){
      const float mn = fmaxf(m_[q], pm[q]);
      const float al = __expf(m_[q] - mn);
      m_[q] = mn;
      l_[q] *= al;
      #pragma unroll
      for (int f = 0; f < 4; ++f) yacc[f][q] *= al;
      float acc = 0.f;
      #pragma unroll
      for (int c = 0; c < 4; ++c){
        const float p = __expf(s[c][q] - mn);
        s[c][q] = p;
        acc += p;
      }
      rs[q] = acc;
    }
    #pragma unroll
    for (int q = 0; q < 4; ++q){
      #pragma unroll
      for (int o = 1; o < 16; o <<= 1)
        rs[q] += __shfl_xor(rs[q], o);
      l_[q] += rs[q];
    }
    #pragma unroll
    for (int c = 0; c < 4; ++c)
      #pragma unroll
      for (int q = 0; q < 4; ++q){
        const int a = swz((g * 4 + q) * 128 + (c * 16 + r) * 2);
        *(bfu*)&plds[a] = f2bf(s[c][q]);
      }
    short8 pa[2];
    #pragma unroll
    for (int ks = 0; ks < 2; ++ks)
      pa[ks] = *(const short8*)&plds[swz(r * 128 + ks * 64 + g * 16)];
    #pragma unroll
    for (int f = 0; f < 4; ++f){
      const short8 vf0 = *(const short8*)(lV + off[f][0]);
      const short8 vf1 = *(const short8*)(lV + off[f][1]);
      yacc[f] = mfma16(pa[0], vf0, yacc[f]);
      yacc[f] = mfma16(pa[1], vf1, yacc[f]);
    }
    __syncthreads();
  }

  bfu* yb = y + (size_t)(b * SEQ + q128 * 128 + wave * 16) * DIM + h * 64;
  #pragma unroll
  for (int f = 0; f < 4; ++f)
    #pragma unroll
    for (int q = 0; q < 4; ++q)
      yb[(size_t)(g * 4 + q) * DIM + f * 16 + r] = f2bf(yacc[f][q] / l_[q]);
}

// ---------------- launch ----------------
extern "C" void kernel_launch(void* const* d_in, const int* in_sizes, int n_in,
                              void* d_out, int out_size, void* d_ws, size_t ws_size,
                              hipStream_t stream) {
  const float* x      = (const float*)d_in[0];
  const float* ln1ag  = (const float*)d_in[1];
  const float* ln1ab  = (const float*)d_in[2];
  const float* ln1bg  = (const float*)d_in[3];
  const float* ln1bb  = (const float*)d_in[4];
  const float* ln1cg  = (const float*)d_in[5];
  const float* ln1cb  = (const float*)d_in[6];
  const float* ln2ag  = (const float*)d_in[7];
  const float* ln2ab  = (const float*)d_in[8];
  const float* ln2bg  = (const float*)d_in[9];
  const float* ln2bb  = (const float*)d_in[10];
  const float* ln2cg  = (const float*)d_in[11];
  const float* ln2cb  = (const float*)d_in[12];
  const float* qkv_w  = (const float*)d_in[13];
  const float* proj_w = (const float*)d_in[14];
  const float* proj_b = (const float*)d_in[15];
  const float* fc1_w  = (const float*)d_in[16];
  const float* fc1_b  = (const float*)d_in[17];
  const float* fc2_w  = (const float*)d_in[18];
  const float* fc2_b  = (const float*)d_in[19];
  float* outp = (float*)d_out;

  char* ws = (char*)d_ws;
  bfu* wqkv   = (bfu*)(ws + 0);            // 2304*768*2  = 3,538,944
  bfu* wproj  = (bfu*)(ws + 3538944);      //  768*768*2  = 1,179,648
  bfu* wfc1   = (bfu*)(ws + 4718592);      // 3072*768*2  = 4,718,592
  bfu* wfc2   = (bfu*)(ws + 9437184);      //  768*3072*2 = 4,718,592
  bfu* lnbuf  = (bfu*)(ws + 14155776);     // 8192*768*2  = 12,582,912
  bfu* ybuf   = (bfu*)(ws + 26738688);     // 8192*768*2  = 12,582,912
  bfu* qkvbuf = (bfu*)(ws + 39321600);     // 8192*2304*2 = 37,748,736
  bfu* vtbuf  = (bfu*)(ws + 77070336);     // 96*64*1024*2= 12,582,912  (end ~89.7MB)
  bfu* hbuf   = qkvbuf;                    // reuse qkv+vt region: 8192*3072*2 = 50,331,648

  // weights -> bf16 (single launch)
  cvt_all<<<2048, 256, 0, stream>>>((const float4*)qkv_w,  (ushort4*)wqkv,
                                    (const float4*)proj_w, (ushort4*)wproj,
                                    (const float4*)fc1_w,  (ushort4*)wfc1,
                                    (const float4*)fc2_w,  (ushort4*)wfc2);

  // LN1
  ln_split<<<NTOK, 256, 0, stream>>>(x, ln1ag, ln1ab, ln1bg, ln1bb, ln1cg, ln1cb, lnbuf);
  // QKV (Q scaled by 0.125 in epilogue): 64x18 = 1152 blocks
  gemm_qkv<<<1152, 256, 0, stream>>>(lnbuf, wqkv, qkvbuf);
  // V transpose for PV B-operand
  vtrans<<<dim3(96,16), 256, 0, stream>>>(qkvbuf, vtbuf);
  // attention (staged K/V, double-buffered)
  attn2<<<768, 512, 0, stream>>>(qkvbuf, vtbuf, ybuf);
  // proj + bias + residual(x) -> d_out (fp32): 128x6 = 768 blocks (64x128 tile)
  gemm_proj<<<768, 256, 0, stream>>>(ybuf, wproj, proj_b, x, outp);
  // LN2
  ln_split<<<NTOK, 256, 0, stream>>>(outp, ln2ag, ln2ab, ln2bg, ln2bb, ln2cg, ln2cb, lnbuf);
  // FC1 + bias + GELU -> h (bf16): 64x24 = 1536 blocks
  gemm_fc1<<<1536, 256, 0, stream>>>(lnbuf, wfc1, fc1_b, hbuf);
  // FC2 + bias + residual(d_out) -> d_out (fp32, in-place): 128x6 = 768 blocks
  gemm_fc2<<<768, 256, 0, stream>>>(hbuf, wfc2, fc2_b, outp);
}

// Round 8
// 409.600 us; speedup vs baseline: 1.2707x; 1.1156x over previous
//
#include <hip/hip_runtime.h>
#include <math.h>

// Problem constants
#define NTOK 8192       // B*N tokens
#define DIM 768
#define SEQ 1024
#define NH 12
#define HD 64
#define HID 3072
#define S1V 320
#define S2V 384

typedef unsigned short bfu;   // bf16 storage
typedef __attribute__((ext_vector_type(8))) short short8;
typedef __attribute__((ext_vector_type(4))) float f32x4;

__device__ __forceinline__ bfu f2bf(float f){
  unsigned int u = __float_as_uint(f);
  u += 0x7FFFu + ((u >> 16) & 1u);      // RNE
  return (bfu)(u >> 16);
}
__device__ __forceinline__ f32x4 mfma16(short8 a, short8 b, f32x4 c){
  return __builtin_amdgcn_mfma_f32_16x16x32_bf16(a, b, c, 0, 0, 0);
}
__device__ __forceinline__ void gll16(const void* g, void* l){
  __builtin_amdgcn_global_load_lds(
      (const __attribute__((address_space(1))) unsigned int*)g,
      (__attribute__((address_space(3))) unsigned int*)l, 16, 0, 0);
}
// XOR-swizzle: fold bits[9:7] (row%8 for 128B rows) into 16B-slot bits[6:4].
// Involution; preserves bits [3:0] so 16B accesses stay contiguous.
__device__ __forceinline__ int swz(int a){ return a ^ (((a >> 7) & 7) << 4); }

// ---------------- fp32 -> bf16 convert (all four weights, one launch) ----------------
__global__ __launch_bounds__(256) void cvt_all(
    const float4* __restrict__ s0, ushort4* __restrict__ d0,   // qkv_w  442368 f4
    const float4* __restrict__ s1, ushort4* __restrict__ d1,   // proj_w 147456
    const float4* __restrict__ s2, ushort4* __restrict__ d2,   // fc1_w  589824
    const float4* __restrict__ s3, ushort4* __restrict__ d3)   // fc2_w  589824
{
  const int total = 1769472;
  for (int i = blockIdx.x * 256 + threadIdx.x; i < total; i += gridDim.x * 256){
    const float4* s; ushort4* d; int j = i;
    if (j < 442368)       { s = s0; d = d0; }
    else if (j < 589824)  { s = s1; d = d1; j -= 442368; }
    else if (j < 1179648) { s = s2; d = d2; j -= 589824; }
    else                  { s = s3; d = d3; j -= 1179648; }
    float4 f = s[j];
    ushort4 o;
    o.x = f2bf(f.x); o.y = f2bf(f.y); o.z = f2bf(f.z); o.w = f2bf(f.w);
    d[j] = o;
  }
}

// ---------------- split LayerNorm: segments [0,320),[320,384),[384,768) ----------------
__global__ __launch_bounds__(256) void ln_split(
    const float* __restrict__ x,
    const float* __restrict__ ga, const float* __restrict__ ba,
    const float* __restrict__ gb, const float* __restrict__ bb2,
    const float* __restrict__ gc, const float* __restrict__ bc,
    bfu* __restrict__ out)
{
  const int row = blockIdx.x, t = threadIdx.x;
  const float* xr = x + (size_t)row * DIM;
  const float e0 = xr[t], e1 = xr[t + 256], e2 = xr[t + 512];
  float s0 = e0, q0 = e0 * e0, s1 = 0.f, q1 = 0.f, s2 = e2, q2 = e2 * e2;
  const int i1 = t + 256;
  if (i1 < S1V)      { s0 += e1; q0 += e1 * e1; }
  else if (i1 < S2V) { s1 += e1; q1 += e1 * e1; }
  else               { s2 += e1; q2 += e1 * e1; }
  float v[6] = {s0, q0, s1, q1, s2, q2};
  #pragma unroll
  for (int k = 0; k < 6; ++k)
    #pragma unroll
    for (int off = 32; off; off >>= 1)
      v[k] += __shfl_xor(v[k], off);
  __shared__ float red[6][4];
  const int lane = t & 63, wave = t >> 6;
  if (lane == 0){
    #pragma unroll
    for (int k = 0; k < 6; ++k) red[k][wave] = v[k];
  }
  __syncthreads();
  float tt[6];
  #pragma unroll
  for (int k = 0; k < 6; ++k) tt[k] = red[k][0] + red[k][1] + red[k][2] + red[k][3];
  const float m0 = tt[0] * (1.f/320.f);
  const float r0 = rsqrtf(tt[1] * (1.f/320.f) - m0*m0 + 1e-5f);
  const float m1 = tt[2] * (1.f/64.f);
  const float r1 = rsqrtf(tt[3] * (1.f/64.f) - m1*m1 + 1e-5f);
  const float m2 = tt[4] * (1.f/384.f);
  const float r2 = rsqrtf(tt[5] * (1.f/384.f) - m2*m2 + 1e-5f);
  bfu* orow = out + (size_t)row * DIM;
  orow[t] = f2bf((e0 - m0) * r0 * ga[t] + ba[t]);
  {
    float ov;
    if (i1 < S1V)      ov = (e1 - m0) * r0 * ga[i1] + ba[i1];
    else if (i1 < S2V) ov = (e1 - m1) * r1 * gb[i1 - S1V] + bb2[i1 - S1V];
    else               ov = (e1 - m2) * r2 * gc[i1 - S2V] + bc[i1 - S2V];
    orow[i1] = f2bf(ov);
  }
  const int i2 = t + 512;
  orow[i2] = f2bf((e2 - m2) * r2 * gc[i2 - S2V] + bc[i2 - S2V]);
}

// ---------------- GEMM core v3: BM x 128 tile, BK=64, 4 waves (2x2), counted vmcnt ------
// Combines round-3's proven deep loop (39%/busy-CU) with round-6's grid fill.
// Per iter: [wait own vmcnt -> s_barrier] -> ds_read frags -> MFMA(2 K-halves)
//           -> s_barrier -> stage tile t+2 into the just-freed slot.
// Per-wave vmcnt ledger: entering iter t, outstanding = tile (t+1)'s AB loads
// (issued one full iteration earlier) -> wait vmcnt(AB); last iter waits 0.
// LDS: BM=128 -> 64KB (2 blocks/CU); BM=64 -> 48KB (3 blocks/CU).
template<int BM, int BIAS, int GELU_, int RESID, int OUTF32, int QSC>
__device__ __forceinline__ void gemm_core64(
    const bfu* __restrict__ A, const bfu* __restrict__ Bw,
    int N, int K, int ntn,
    const float* __restrict__ bias, const float* __restrict__ resid,
    float* __restrict__ outf, bfu* __restrict__ outb)
{
  constexpr int FM = BM / 32;            // A-frag rows per wave (wave tile = BM/2 x 64)
  constexpr int AISS = BM / 32;          // gll16 issues for A half (BM*128B / 4096)
  constexpr int BISS = 4;                // 128*128B / 4096
  constexpr int AB = AISS + BISS;
  __shared__ __align__(16) char lA_[2][BM * 128];
  __shared__ __align__(16) char lB_[2][128 * 128];
  const int tid = threadIdx.x;
  const int lane = tid & 63;
  const int wave = tid >> 6;
  const int wm = wave >> 1, wn = wave & 1;
  const int r = lane & 15, g = lane >> 4;

  // T1 XCD-aware grid swizzle (all grids % 8 == 0)
  const int nwg = gridDim.x, cpx = nwg >> 3;
  const int sb = (blockIdx.x & 7) * cpx + (blockIdx.x >> 3);
  const int tm = sb / ntn, tn = sb % ntn;
  const size_t ld2 = (size_t)K * 2;

  f32x4 acc[FM][4];
  #pragma unroll
  for (int i = 0; i < FM; ++i)
    #pragma unroll
    for (int j = 0; j < 4; ++j) acc[i][j] = (f32x4){0.f, 0.f, 0.f, 0.f};

  // staging geometry: 256 thr x 16B = 4KB = 32 rows(128B) per issue; src pre-swizzled
  const int Ls = swz(tid * 16);
  const int srow = Ls >> 7, scol = Ls & 127;
  const char* Abase = (const char*)A + (size_t)tm * BM * ld2 + scol;
  const char* Bbase = (const char*)Bw + (size_t)tn * 128 * ld2 + scol;
  const int tid16 = tid * 16;
  const int nt = K >> 6;

  #define STG(slot, t) do { \
    _Pragma("unroll") \
    for (int is = 0; is < AISS; ++is) \
      gll16(Abase + (size_t)(is * 32 + srow) * ld2 + (size_t)(t) * 128, \
            &lA_[slot][is * 4096 + tid16]); \
    _Pragma("unroll") \
    for (int is = 0; is < BISS; ++is) \
      gll16(Bbase + (size_t)(is * 32 + srow) * ld2 + (size_t)(t) * 128, \
            &lB_[slot][is * 4096 + tid16]); \
  } while (0)

  // fragment read offsets (loop-invariant, swizzled); rows are 128B (BK=64)
  int offA[FM][2], offB[4][2];
  #pragma unroll
  for (int f = 0; f < FM; ++f)
    #pragma unroll
    for (int h = 0; h < 2; ++h)
      offA[f][h] = swz((wm * (BM / 2) + f * 16 + r) * 128 + h * 64 + g * 16);
  #pragma unroll
  for (int j = 0; j < 4; ++j)
    #pragma unroll
    for (int h = 0; h < 2; ++h)
      offB[j][h] = swz((wn * 64 + j * 16 + r) * 128 + h * 64 + g * 16);

  // prologue: tiles 0 and 1
  STG(0, 0);
  STG(1, 1);

  for (int t = 0; t < nt; ++t){
    const int s = t & 1;
    if (t + 1 < nt){
      if constexpr (AB == 8) asm volatile("s_waitcnt vmcnt(8)" ::: "memory");
      else                   asm volatile("s_waitcnt vmcnt(6)" ::: "memory");
    } else {
      asm volatile("s_waitcnt vmcnt(0)" ::: "memory");
    }
    __builtin_amdgcn_sched_barrier(0);
    __builtin_amdgcn_s_barrier();          // all waves' tile-t loads landed

    const char* lA = lA_[s];
    const char* lB = lB_[s];
    short8 af[FM][2], bf[4][2];
    #pragma unroll
    for (int f = 0; f < FM; ++f)
      #pragma unroll
      for (int h = 0; h < 2; ++h)
        af[f][h] = *(const short8*)(lA + offA[f][h]);
    #pragma unroll
    for (int j = 0; j < 4; ++j)
      #pragma unroll
      for (int h = 0; h < 2; ++h)
        bf[j][h] = *(const short8*)(lB + offB[j][h]);

    __builtin_amdgcn_s_setprio(1);
    #pragma unroll
    for (int h = 0; h < 2; ++h)
      #pragma unroll
      for (int i = 0; i < FM; ++i)
        #pragma unroll
        for (int j = 0; j < 4; ++j)
          acc[i][j] = mfma16(af[i][h], bf[j][h], acc[i][j]);
    __builtin_amdgcn_s_setprio(0);

    __builtin_amdgcn_s_barrier();          // all waves done reading slot s
    if (t + 2 < nt) STG(s, t + 2);         // refill freed slot, full-iter lead
  }
  #undef STG

  // epilogue: C/D layout col=lane&15(r), row=(lane>>4)*4+q
  const int row0 = tm * BM + wm * (BM / 2);
  const int col0 = tn * 128 + wn * 64;
  #pragma unroll
  for (int j = 0; j < 4; ++j){
    const int colb = col0 + j * 16 + r;
    const float bi = BIAS ? bias[colb] : 0.f;
    #pragma unroll
    for (int i = 0; i < FM; ++i){
      #pragma unroll
      for (int q = 0; q < 4; ++q){
        const int rowg = row0 + i * 16 + g * 4 + q;
        float v = acc[i][j][q] + bi;
        if (GELU_) v = 0.5f * v * (1.f + erff(v * 0.70710678118654752440f));
        if (QSC && colb < 768) v *= 0.125f;   // fold attention scale into Q
        const size_t idx = (size_t)rowg * N + colb;
        if (RESID) v += resid[idx];
        if (OUTF32) outf[idx] = v;
        else        outb[idx] = f2bf(v);
      }
    }
  }
}

// Named wrappers -> distinct Kernel_Name rows in rocprof
__global__ __launch_bounds__(256, 2) void gemm_qkv(const bfu* A, const bfu* Bw, bfu* out){
  gemm_core64<128,0,0,0,0,1>(A, Bw, 2304, 768, 18, nullptr, nullptr, nullptr, out);
}
__global__ __launch_bounds__(256, 2) void gemm_proj(const bfu* A, const bfu* Bw,
                                                    const float* bias, const float* resid, float* out){
  gemm_core64<64,1,0,1,1,0>(A, Bw, 768, 768, 6, bias, resid, out, nullptr);
}
__global__ __launch_bounds__(256, 2) void gemm_fc1(const bfu* A, const bfu* Bw,
                                                   const float* bias, bfu* out){
  gemm_core64<128,1,1,0,0,0>(A, Bw, 3072, 768, 24, bias, nullptr, nullptr, out);
}
__global__ __launch_bounds__(256, 2) void gemm_fc2(const bfu* A, const bfu* Bw,
                                                   const float* bias, float* out){
  gemm_core64<64,1,0,1,1,0>(A, Bw, 768, 3072, 6, bias, out, out, nullptr);
}

// ---------------- V transpose: qkv[:,1536+h*64+d] -> vt[bh][d][k] ----------------
__global__ __launch_bounds__(256) void vtrans(const bfu* __restrict__ qkv, bfu* __restrict__ vt){
  __shared__ bfu tile[64][66];
  const int bh = blockIdx.x, kt = blockIdx.y;
  const int b = bh / NH, h = bh - b * NH;
  const int tid = threadIdx.x;
  const int tr = tid >> 5;
  const int tc = (tid & 31) * 2;
  #pragma unroll
  for (int pass = 0; pass < 8; ++pass){
    const int k = pass * 8 + tr;
    const bfu* src = qkv + (size_t)(b * SEQ + kt * 64 + k) * 2304 + 1536 + h * 64 + tc;
    tile[k][tc] = src[0]; tile[k][tc + 1] = src[1];
  }
  __syncthreads();
  #pragma unroll
  for (int pass = 0; pass < 8; ++pass){
    const int d = pass * 8 + tr;
    bfu* dst = vt + ((size_t)bh * 64 + d) * SEQ + kt * 64 + tc;
    dst[0] = tile[tc][d]; dst[1] = tile[tc + 1][d];
  }
}

// ---------------- flash attention v2: 8 waves/block, LDS-staged K/V, double-buffered ----------
__global__ __launch_bounds__(512) void attn2(
    const bfu* __restrict__ qkv, const bfu* __restrict__ vt, bfu* __restrict__ y)
{
  __shared__ __align__(16) char kbuf[2][8192];
  __shared__ __align__(16) char vbuf[2][8192];
  __shared__ __align__(16) char plds_all[8][2048];
  const int tid = threadIdx.x, lane = tid & 63, wave = tid >> 6;
  char* plds = plds_all[wave];
  const int blk = blockIdx.x;                 // 768 blocks
  const int bh = blk >> 3, q128 = blk & 7;
  const int b = bh / NH, h = bh - b * NH;
  const int r = lane & 15, g = lane >> 4;

  const bfu* qbase = qkv + (size_t)(b * SEQ + q128 * 128 + wave * 16 + r) * 2304 + h * 64;
  const short8 qf0 = *(const short8*)(qbase + g * 8);
  const short8 qf1 = *(const short8*)(qbase + 32 + g * 8);

  const int P = tid * 16;
  const int Ls = swz(P);
  const int srow = Ls >> 7, scol = Ls & 127;
  const char* kg = (const char*)(qkv + (size_t)(b * SEQ) * 2304 + 768 + h * 64)
                   + (size_t)srow * 4608 + scol;
  const char* vg = (const char*)(vt + (size_t)bh * 64 * SEQ)
                   + (size_t)srow * 2048 + scol;

  int off[4][2];
  #pragma unroll
  for (int f = 0; f < 4; ++f){
    off[f][0] = swz((f * 16 + r) * 128 + g * 16);
    off[f][1] = swz((f * 16 + r) * 128 + 64 + g * 16);
  }

  float m_[4], l_[4];
  f32x4 yacc[4];
  #pragma unroll
  for (int i = 0; i < 4; ++i){ m_[i] = -1e30f; l_[i] = 0.f; yacc[i] = (f32x4){0.f,0.f,0.f,0.f}; }

  gll16(kg, &kbuf[0][P]);
  gll16(vg, &vbuf[0][P]);
  __syncthreads();

  for (int kt = 0; kt < 16; ++kt){
    const int cur = kt & 1;
    if (kt + 1 < 16){
      gll16(kg + (size_t)(kt + 1) * 294912, &kbuf[cur ^ 1][P]);   // 64 rows * 4608B
      gll16(vg + (kt + 1) * 128, &vbuf[cur ^ 1][P]);
    }
    const char* lK = kbuf[cur];
    const char* lV = vbuf[cur];

    f32x4 s[4];
    #pragma unroll
    for (int c = 0; c < 4; ++c){
      const short8 kf0 = *(const short8*)(lK + off[c][0]);
      const short8 kf1 = *(const short8*)(lK + off[c][1]);
      s[c] = (f32x4){0.f, 0.f, 0.f, 0.f};
      s[c] = mfma16(qf0, kf0, s[c]);
      s[c] = mfma16(qf1, kf1, s[c]);
    }
    float pm[4];
    #pragma unroll
    for (int q = 0; q < 4; ++q)
      pm[q] = fmaxf(fmaxf(s[0][q], s[1][q]), fmaxf(s[2][q], s[3][q]));
    #pragma unroll
    for (int q = 0; q < 4; ++q)
      #pragma unroll
      for (int o = 1; o < 16; o <<= 1)
        pm[q] = fmaxf(pm[q], __shfl_xor(pm[q], o));
    float rs[4];
    #pragma unroll
    for (int q = 0; q < 4; ++q){
      const float mn = fmaxf(m_[q], pm[q]);
      const float al = __expf(m_[q] - mn);
      m_[q] = mn;
      l_[q] *= al;
      #pragma unroll
      for (int f = 0; f < 4; ++f) yacc[f][q] *= al;
      float acc = 0.f;
      #pragma unroll
      for (int c = 0; c < 4; ++c){
        const float p = __expf(s[c][q] - mn);
        s[c][q] = p;
        acc += p;
      }
      rs[q] = acc;
    }
    #pragma unroll
    for (int q = 0; q < 4; ++q){
      #pragma unroll
      for (int o = 1; o < 16; o <<= 1)
        rs[q] += __shfl_xor(rs[q], o);
      l_[q] += rs[q];
    }
    #pragma unroll
    for (int c = 0; c < 4; ++c)
      #pragma unroll
      for (int q = 0; q < 4; ++q){
        const int a = swz((g * 4 + q) * 128 + (c * 16 + r) * 2);
        *(bfu*)&plds[a] = f2bf(s[c][q]);
      }
    short8 pa[2];
    #pragma unroll
    for (int ks = 0; ks < 2; ++ks)
      pa[ks] = *(const short8*)&plds[swz(r * 128 + ks * 64 + g * 16)];
    #pragma unroll
    for (int f = 0; f < 4; ++f){
      const short8 vf0 = *(const short8*)(lV + off[f][0]);
      const short8 vf1 = *(const short8*)(lV + off[f][1]);
      yacc[f] = mfma16(pa[0], vf0, yacc[f]);
      yacc[f] = mfma16(pa[1], vf1, yacc[f]);
    }
    __syncthreads();
  }

  bfu* yb = y + (size_t)(b * SEQ + q128 * 128 + wave * 16) * DIM + h * 64;
  #pragma unroll
  for (int f = 0; f < 4; ++f)
    #pragma unroll
    for (int q = 0; q < 4; ++q)
      yb[(size_t)(g * 4 + q) * DIM + f * 16 + r] = f2bf(yacc[f][q] / l_[q]);
}

// ---------------- launch ----------------
extern "C" void kernel_launch(void* const* d_in, const int* in_sizes, int n_in,
                              void* d_out, int out_size, void* d_ws, size_t ws_size,
                              hipStream_t stream) {
  const float* x      = (const float*)d_in[0];
  const float* ln1ag  = (const float*)d_in[1];
  const float* ln1ab  = (const float*)d_in[2];
  const float* ln1bg  = (const float*)d_in[3];
  const float* ln1bb  = (const float*)d_in[4];
  const float* ln1cg  = (const float*)d_in[5];
  const float* ln1cb  = (const float*)d_in[6];
  const float* ln2ag  = (const float*)d_in[7];
  const float* ln2ab  = (const float*)d_in[8];
  const float* ln2bg  = (const float*)d_in[9];
  const float* ln2bb  = (const float*)d_in[10];
  const float* ln2cg  = (const float*)d_in[11];
  const float* ln2cb  = (const float*)d_in[12];
  const float* qkv_w  = (const float*)d_in[13];
  const float* proj_w = (const float*)d_in[14];
  const float* proj_b = (const float*)d_in[15];
  const float* fc1_w  = (const float*)d_in[16];
  const float* fc1_b  = (const float*)d_in[17];
  const float* fc2_w  = (const float*)d_in[18];
  const float* fc2_b  = (const float*)d_in[19];
  float* outp = (float*)d_out;

  char* ws = (char*)d_ws;
  bfu* wqkv   = (bfu*)(ws + 0);            // 2304*768*2  = 3,538,944
  bfu* wproj  = (bfu*)(ws + 3538944);      //  768*768*2  = 1,179,648
  bfu* wfc1   = (bfu*)(ws + 4718592);      // 3072*768*2  = 4,718,592
  bfu* wfc2   = (bfu*)(ws + 9437184);      //  768*3072*2 = 4,718,592
  bfu* lnbuf  = (bfu*)(ws + 14155776);     // 8192*768*2  = 12,582,912
  bfu* ybuf   = (bfu*)(ws + 26738688);     // 8192*768*2  = 12,582,912
  bfu* qkvbuf = (bfu*)(ws + 39321600);     // 8192*2304*2 = 37,748,736
  bfu* vtbuf  = (bfu*)(ws + 77070336);     // 96*64*1024*2= 12,582,912  (end ~89.7MB)
  bfu* hbuf   = qkvbuf;                    // reuse qkv+vt region: 8192*3072*2 = 50,331,648

  // weights -> bf16 (single launch)
  cvt_all<<<2048, 256, 0, stream>>>((const float4*)qkv_w,  (ushort4*)wqkv,
                                    (const float4*)proj_w, (ushort4*)wproj,
                                    (const float4*)fc1_w,  (ushort4*)wfc1,
                                    (const float4*)fc2_w,  (ushort4*)wfc2);

  // LN1
  ln_split<<<NTOK, 256, 0, stream>>>(x, ln1ag, ln1ab, ln1bg, ln1bb, ln1cg, ln1cb, lnbuf);
  // QKV (Q scaled by 0.125 in epilogue): 64x18 = 1152 blocks, 2 blocks/CU
  gemm_qkv<<<1152, 256, 0, stream>>>(lnbuf, wqkv, qkvbuf);
  // V transpose for PV B-operand
  vtrans<<<dim3(96,16), 256, 0, stream>>>(qkvbuf, vtbuf);
  // attention (staged K/V, double-buffered)
  attn2<<<768, 512, 0, stream>>>(qkvbuf, vtbuf, ybuf);
  // proj + bias + residual(x) -> d_out (fp32): 128x6 = 768 blocks, 3 blocks/CU
  gemm_proj<<<768, 256, 0, stream>>>(ybuf, wproj, proj_b, x, outp);
  // LN2
  ln_split<<<NTOK, 256, 0, stream>>>(outp, ln2ag, ln2ab, ln2bg, ln2bb, ln2cg, ln2cb, lnbuf);
  // FC1 + bias + GELU -> h (bf16): 64x24 = 1536 blocks, 2 blocks/CU
  gemm_fc1<<<1536, 256, 0, stream>>>(lnbuf, wfc1, fc1_b, hbuf);
  // FC2 + bias + residual(d_out) -> d_out (fp32, in-place): nt=48 deep, 768 blocks
  gemm_fc2<<<768, 256, 0, stream>>>(hbuf, wfc2, fc2_b, outp);
}